// Round 8
// baseline (129.240 us; speedup 1.0000x reference)
//
#include <hip/hip_runtime.h>

// SSIM, N=32 images 512x512 fp32, 11x11 Gaussian (separable via rank-1
// window), zero pad, scalar mean output.
//
// R17: SOFTWARE-PIPELINED LDS READS. R9-R16 post-mortem: wall pinned at
// 43-46us while occupancy varied 16->27% -- occupancy is not the lever.
// The model that fits all rounds: per-CU VALU busy ~20us + LDS pipe time
// ~13-21us + exposed HBM ~ wall. The pipes run SERIALLY because each
// iteration is ds_read(row i) -> lgkm wait -> VALU(row i): reads and
// compute of the same row are one dependence chain, and the i>=10 epilogue
// branch splits BBs so the compiler never hoists iter i+1's reads above
// iter i's VALU. Every wave alternates LDS-phase/VALU-phase; identical
// waves alternate in phase; wall = sum of pipes.
// Fix: double-buffered window regs eA/eB (static s%2 select). At the TOP
// of iter i, issue the 11 ds_reads for row i+1 into the spare buffer; then
// stage row i+2, issue global loads, and run VALU on the buffer read one
// iteration ago (~400cy lgkm slack -> no stall; LDS pipe busy under VALU).
// LOADROW is branchless (clamped row + select) so the pre-epilogue body is
// one straight-line BB. Slot ring distances re-derived: write@i row i+2 ->
// slot (i+2)%3, prefetch-read@i row i+1 <- slot (i+1)%3 (written @ i-1,
// ~1 iter gap); tail iters read/write never-consumed slots (checked).
// Cost: +22 regs (eB), +8% tail fetch (unguarded prefetch, LLC-absorbed).
// Kept from R16: M=1 col/thread, wave-private 3-slot ring, depth-2 global
// prefetch, 12-slot vertical ring, (s,d)=(x+y,x-y) packed trick, unroll-12
// inner + `#pragma unroll 1` outer (all %12 %3 %2 static -- R10 lesson),
// no main-loop barriers (R12), grid (28,32)=896 4-wave blocks.
// No min-waves launch_bounds (R3: forced cap => spill).

typedef float v2f __attribute__((ext_vector_type(2)));

#define IMG_H 512
#define IMG_W 512
#define NIMG  32
#define NT    256
#define RROWS 38
#define NCHNK 14             // ceil(512/38): last chunk outputs 18 rows
#define ITERS 48             // RROWS+10 = 4 x 12 exactly
// per-wave LDS slot: idx 0..73 hold (s,d) of cols C0-5 .. C0+68
// (idx k <-> col C0-5+k). 74 used, pad stride to 80 v2f (640 B).
#define SLOTW 80

#define C1F  1.0e-4f
#define C2F  9.0e-4f
#define EPSF 1.0e-8f

static __device__ __forceinline__ v2f pkfma(float s, v2f a, v2f b) {
    v2f sv = {s, s};
    return __builtin_elementwise_fma(sv, a, b);   // -> v_pk_fma_f32
}

__global__ __launch_bounds__(NT) void ssim_kernel(
    const float* __restrict__ xg, const float* __restrict__ yg,
    const float* __restrict__ wg, float* __restrict__ out)
{
    const int t    = threadIdx.x;       // 0..255
    const int lane = t & 63;
    const int wv   = t >> 6;            // wave id 0..3
    const int bx   = blockIdx.x;        // 0..27
    const int img  = blockIdx.y;        // 0..31
    const int chnk = bx >> 1;           // 0..13
    const int seg  = ((bx & 1) << 2) | wv;   // 0..7: block = 4 adjacent segs
    const int r0   = chnk * RROWS;
    const int C0   = seg * 64;          // segment col base
    const int cown = C0 + lane;         // owned col

    const float* xb = xg + (size_t)img * (IMG_H * IMG_W);
    const float* yb = yg + (size_t)img * (IMG_H * IMG_W);

    __shared__ alignas(16) v2f seg3[4][3][SLOTW];   // 4 waves x 3 slots, 7.5KB
    __shared__ float wredS[4];

    // 1D taps = row sums of normalized 2D window -> SGPRs via readfirstlane.
    float rs = 0.f;
    if (lane < 11) {
        #pragma unroll
        for (int j = 0; j < 11; ++j) rs += wg[lane * 11 + j];
    }
    float g[11];
    #pragma unroll
    for (int k = 0; k < 11; ++k) {
        int gi = __shfl(__float_as_int(rs), k, 64);
        g[k] = __int_as_float(__builtin_amdgcn_readfirstlane(gi));
    }

    // halo duty: lanes 0..4 left (col C0-5+lane, idx lane), lanes 59..63
    // right (col C0+64+(lane-59), idx lane+10). Out-of-image -> 0.
    const bool isH  = (lane < 5) || (lane >= 59);
    const int  hcol = (lane < 5) ? (C0 - 5 + lane) : (C0 + 64 + (lane - 59));
    const int  hidx = (lane < 5) ? lane : (lane + 10);
    const int  hc   = hcol < 0 ? 0 : (hcol > IMG_W - 1 ? IMG_W - 1 : hcol);
    const bool hinW = ((unsigned)hcol < IMG_W);

    // pending-row registers, depth 2 (scalars: M=1)
    float px0, py0, hx0, hy0;
    float px1, py1, hx1, hy1;

// branchless: clamped-row loads always issue; zero via select.
#define LOADROW(ROW, SUF) do {                                             \
        const int r_  = (ROW);                                             \
        const int rc_ = r_ < 0 ? 0 : (r_ > IMG_H - 1 ? IMG_H - 1 : r_);    \
        const bool ok_ = ((unsigned)r_ < IMG_H);                           \
        const float* xr_ = xb + (size_t)rc_ * IMG_W;                       \
        const float* yr_ = yb + (size_t)rc_ * IMG_W;                       \
        const float a_ = xr_[cown];                                        \
        const float b_ = yr_[cown];                                        \
        px##SUF = ok_ ? a_ : 0.f;                                          \
        py##SUF = ok_ ? b_ : 0.f;                                          \
        hx##SUF = 0.f; hy##SUF = 0.f;                                      \
        if (isH) {                                                         \
            const float c_ = xr_[hc];                                      \
            const float d_ = yr_[hc];                                      \
            const bool hok_ = ok_ && hinW;                                 \
            hx##SUF = hok_ ? c_ : 0.f;                                     \
            hy##SUF = hok_ ? d_ : 0.f;                                     \
        }                                                                  \
    } while (0)

#define WRITESLOT(SL, SUF) do {                                            \
        v2f sd_ = {px##SUF + py##SUF, px##SUF - py##SUF};                  \
        seg3[wv][(SL)][5 + lane] = sd_;                                    \
        if (isH) {                                                         \
            v2f hsd_ = {hx##SUF + hy##SUF, hx##SUF - hy##SUF};             \
            seg3[wv][(SL)][hidx] = hsd_;                                   \
        }                                                                  \
    } while (0)

    // prologue: rows 0,1 (r0-5, r0-4) -> slots 0,1; rows 2,3 pending P0,P1;
    // preload eA <- slot 0 (row 0).
    LOADROW(r0 - 5, 0);
    LOADROW(r0 - 4, 1);
    WRITESLOT(0, 0);
    WRITESLOT(1, 1);
    LOADROW(r0 - 3, 0);     // P0 = streamed row 2
    LOADROW(r0 - 2, 1);     // P1 = streamed row 3

    v2f eA[11], eB[11];     // double-buffered horizontal window
    #pragma unroll
    for (int j = 0; j < 11; ++j) eA[j] = seg3[wv][0][lane + j];

    // vertical register rings, 12 slots (11 + 1 pad for static %12): 48 fl
    v2f rSD[12], rQ[12];

    float acc = 0.f;

    #pragma unroll 1
    for (int base = 0; base < ITERS; base += 12) {
        #pragma unroll
        for (int s = 0; s < 12; ++s) {
            const int i = base + s;     // streamed-row index; i%12==s,
                                        // i%3==s%3, i%2==s%2 (base %12==0)

            // ---- 1. prefetch row i+1's window into the SPARE buffer ----
            // (consumed next iteration; LDS pipe runs under this iter's VALU)
            if (s % 2 == 0) {
                #pragma unroll
                for (int j = 0; j < 11; ++j)
                    eB[j] = seg3[wv][(s + 1) % 3][lane + j];
            } else {
                #pragma unroll
                for (int j = 0; j < 11; ++j)
                    eA[j] = seg3[wv][(s + 1) % 3][lane + j];
            }

            // ---- 2. stage row i+2 from P[i%2] (loaded at iter i-2) ----
            if (s % 2 == 0) WRITESLOT((s + 2) % 3, 0);
            else            WRITESLOT((s + 2) % 3, 1);

            // ---- 3. issue loads for row i+4 into P[i%2] ----
            // (global row r0-5+(i+4) = r0+i-1; tail iters load a clamped
            //  row that is never consumed -- no guard, straight-line)
            if (s % 2 == 0) LOADROW(r0 - 1 + i, 0);
            else            LOADROW(r0 - 1 + i, 1);

            // ---- 4. horizontal conv of row i from the CURRENT buffer ----
            v2f hSD = {0.f, 0.f}, hQ = {0.f, 0.f};
            #pragma unroll
            for (int j = 0; j < 11; ++j) {
                const v2f ej = (s % 2 == 0) ? eA[j] : eB[j];
                const v2f f = ej * ej;              // v_pk_mul_f32
                hSD = pkfma(g[j], ej, hSD);
                hQ  = pkfma(g[j], f,  hQ);
            }
            rSD[s] = hSD;
            rQ[s]  = hQ;

            // ---- 5. vertical conv + SSIM epilogue (row r0 + i - 10) ----
            if (i >= 10) {                       // wave-uniform
                const int orow = r0 + i - 10;
                if (orow < IMG_H) {              // wave-uniform tail guard
                    v2f mSD = {0.f, 0.f}, mQ = {0.f, 0.f};
                    #pragma unroll
                    for (int j = 0; j < 11; ++j) {
                        // input rows i-10+j -> ring slot (i+2+j)%12
                        const int sl = (s + 2 + j) % 12;   // static
                        mSD = pkfma(g[j], rSD[sl], mSD);
                        mQ  = pkfma(g[j], rQ[sl],  mQ);
                    }
                    const v2f t2 = mSD * mSD;      // (mS^2, mD^2)
                    const float a    = 0.5f  * (t2.x + t2.y); // mx2+my2
                    const float muxy = 0.25f * (t2.x - t2.y); // mx*my
                    const float ep   = 0.5f  * (mQ.x + mQ.y); // Ex2+Ey2
                    const float eq   = 0.25f * (mQ.x - mQ.y); // Exy
                    const float sxy  = eq - muxy;
                    const float ssum = ep - a;
                    const float num  = fmaf(2.f, muxy, C1F) * fmaf(2.f, sxy, C2F);
                    const float den  = (a + C1F) * (ssum + C2F);
                    float v = num * __builtin_amdgcn_rcpf(den + EPSF);
                    acc += fminf(fmaxf(v, 0.f), 1.f);
                }
            }
        }
    }

    // block reduction: wave shuffle, 4 slots in LDS, one atomic per block.
    // (The only __syncthreads in the kernel -- at the very end.)
    #pragma unroll
    for (int off = 32; off > 0; off >>= 1)
        acc += __shfl_down(acc, off, 64);
    if (lane == 0) wredS[wv] = acc;
    __syncthreads();
    if (t == 0) {
        const float tot = (wredS[0] + wredS[1]) + (wredS[2] + wredS[3]);
        atomicAdd(out, tot * (1.0f / (float)((size_t)NIMG * IMG_H * IMG_W)));
    }
}

extern "C" void kernel_launch(void* const* d_in, const int* in_sizes, int n_in,
                              void* d_out, int out_size, void* d_ws, size_t ws_size,
                              hipStream_t stream) {
    const float* x = (const float*)d_in[0];
    const float* y = (const float*)d_in[1];
    const float* w = (const float*)d_in[2];
    float* out = (float*)d_out;

    // d_out is re-poisoned to 0xAA before every timed launch; zero it first.
    hipMemsetAsync(out, 0, sizeof(float), stream);

    dim3 grid(NCHNK * 2, NIMG);    // (28, 32) = 896 blocks x 4 waves
    ssim_kernel<<<grid, dim3(NT), 0, stream>>>(x, y, w, out);
}

// Round 9
// 121.710 us; speedup vs baseline: 1.0619x; 1.0619x over previous
//
#include <hip/hip_runtime.h>

// SSIM, N=32 images 512x512 fp32, 11x11 Gaussian (separable via rank-1
// window), zero pad, scalar mean output.
//
// R18: R16 body + two surgical schedule changes (R17 post-mortem: the
// persistent eA/eB double-buffer regressed to 70us -- 44 regs held across
// iterations went to AGPRs, VGPR_Count 60, accvgpr traffic serialized the
// very path being optimized. Lesson: window regs must be SINGLE-VERSION
// and short-lived to stay in VGPRs).
// R16 stall budget: per-wave-iter latency ~1390cy, VALU issue only ~290cy.
// Exposed terms: (a) same-iter ds_read->lgkm->horiz (~150+cy), (b) global
// spacing 2 iters -- fine at 1390cy/iter but marginal (~1000cy) at the
// target iteration rate. Fixes:
//  1. BOTTOM-PREFETCH: the 11 ds_reads move to the bottom of iter i,
//     reading row i+1 into the SAME e[] (dead after horizontal; single
//     version -> VGPRs). Prologue preloads row 0. Issue->use distance:
//     WRITESLOT + LOADROW + epilogue + back-edge (~200+cy cover).
//  2. GLOBAL DEPTH 3: P0/P1/P2 (static s%3, 12%3==0), load row i+5 at
//     iter i, staged at iter i+3: spacing >=1500cy even at 2x iter rate.
// Slot ring re-derived: write row i+2 -> slot (i+2)%3 @ iter i; bottom
// read row i+1 <- slot (i+1)%3 (written @ i-1); iter i+1 overwrites slot
// i%3 AFTER its row-i reads completed (same-wave DS FIFO). Tail iters
// read/write never-consumed slots (checked i=46,47). Guards wave-uniform.
// Kept from R16: M=1 col/thread, (s,d)=(x+y,x-y) packed trick, 12-slot
// vertical ring (static %12 under inner unroll-12, outer unroll 1 -- R10),
// wave-private LDS (no main-loop barriers -- R12), grid (28,32)=896 blocks,
// __launch_bounds__(NT,4).

typedef float v2f __attribute__((ext_vector_type(2)));

#define IMG_H 512
#define IMG_W 512
#define NIMG  32
#define NT    256
#define RROWS 38
#define NCHNK 14             // ceil(512/38): last chunk outputs 18 rows
#define ITERS 48             // RROWS+10 = 4 x 12 exactly
// per-wave LDS slot: idx 0..73 hold (s,d) of cols C0-5 .. C0+68
// (idx k <-> col C0-5+k). 74 used, pad stride to 80 v2f (640 B).
#define SLOTW 80

#define C1F  1.0e-4f
#define C2F  9.0e-4f
#define EPSF 1.0e-8f

static __device__ __forceinline__ v2f pkfma(float s, v2f a, v2f b) {
    v2f sv = {s, s};
    return __builtin_elementwise_fma(sv, a, b);   // -> v_pk_fma_f32
}

__global__ __launch_bounds__(NT, 4) void ssim_kernel(
    const float* __restrict__ xg, const float* __restrict__ yg,
    const float* __restrict__ wg, float* __restrict__ out)
{
    const int t    = threadIdx.x;       // 0..255
    const int lane = t & 63;
    const int wv   = t >> 6;            // wave id 0..3
    const int bx   = blockIdx.x;        // 0..27
    const int img  = blockIdx.y;        // 0..31
    const int chnk = bx >> 1;           // 0..13
    const int seg  = ((bx & 1) << 2) | wv;   // 0..7: block = 4 adjacent segs
    const int r0   = chnk * RROWS;
    const int C0   = seg * 64;          // segment col base
    const int cown = C0 + lane;         // owned col

    const float* xb = xg + (size_t)img * (IMG_H * IMG_W);
    const float* yb = yg + (size_t)img * (IMG_H * IMG_W);

    __shared__ alignas(16) v2f seg3[4][3][SLOTW];   // 4 waves x 3 slots, 7.5KB
    __shared__ float wredS[4];

    // 1D taps = row sums of normalized 2D window -> SGPRs via readfirstlane.
    float rs = 0.f;
    if (lane < 11) {
        #pragma unroll
        for (int j = 0; j < 11; ++j) rs += wg[lane * 11 + j];
    }
    float g[11];
    #pragma unroll
    for (int k = 0; k < 11; ++k) {
        int gi = __shfl(__float_as_int(rs), k, 64);
        g[k] = __int_as_float(__builtin_amdgcn_readfirstlane(gi));
    }

    // halo duty: lanes 0..4 left (col C0-5+lane, idx lane), lanes 59..63
    // right (col C0+64+(lane-59), idx lane+10). Out-of-image -> 0.
    const bool isH  = (lane < 5) || (lane >= 59);
    const int  hcol = (lane < 5) ? (C0 - 5 + lane) : (C0 + 64 + (lane - 59));
    const int  hidx = (lane < 5) ? lane : (lane + 10);

    // pending-row registers, depth 3 (scalars: M=1)
    float px0, py0, hx0, hy0;
    float px1, py1, hx1, hy1;
    float px2, py2, hx2, hy2;

#define LOADROW(ROW, SUF) do {                                             \
        const int r_ = (ROW);                                              \
        px##SUF = 0.f; py##SUF = 0.f; hx##SUF = 0.f; hy##SUF = 0.f;        \
        if ((unsigned)r_ < IMG_H) {                                        \
            const float* xr_ = xb + (size_t)r_ * IMG_W;                    \
            const float* yr_ = yb + (size_t)r_ * IMG_W;                    \
            px##SUF = xr_[cown];                                           \
            py##SUF = yr_[cown];                                           \
            if (isH && (unsigned)hcol < IMG_W) {                           \
                hx##SUF = xr_[hcol];                                       \
                hy##SUF = yr_[hcol];                                       \
            }                                                              \
        }                                                                  \
    } while (0)

#define WRITESLOT(SL, SUF) do {                                            \
        v2f sd_ = {px##SUF + py##SUF, px##SUF - py##SUF};                  \
        seg3[wv][(SL)][5 + lane] = sd_;                                    \
        if (isH) {                                                         \
            v2f hsd_ = {hx##SUF + hy##SUF, hx##SUF - hy##SUF};             \
            seg3[wv][(SL)][hidx] = hsd_;                                   \
        }                                                                  \
    } while (0)

    // prologue: streamed rows 0,1 (r0-5, r0-4) -> slots 0,1;
    // rows 2,3,4 pending in P0,P1,P2; preload e[] <- slot 0 (row 0).
    LOADROW(r0 - 5, 0);
    LOADROW(r0 - 4, 1);
    WRITESLOT(0, 0);
    WRITESLOT(1, 1);
    LOADROW(r0 - 3, 0);     // P0 = streamed row 2 (staged at iter 0)
    LOADROW(r0 - 2, 1);     // P1 = streamed row 3 (staged at iter 1)
    LOADROW(r0 - 1, 2);     // P2 = streamed row 4 (staged at iter 2)

    v2f e[11];              // horizontal window, SINGLE version (VGPRs)
    #pragma unroll
    for (int j = 0; j < 11; ++j) e[j] = seg3[wv][0][lane + j];

    // vertical register rings, 12 slots (11 + 1 pad for static %12): 48 fl
    v2f rSD[12], rQ[12];

    float acc = 0.f;

    #pragma unroll 1
    for (int base = 0; base < ITERS; base += 12) {
        #pragma unroll
        for (int s = 0; s < 12; ++s) {
            const int i = base + s;     // streamed-row index; i%12==s,
                                        // i%3==s%3, i%2==s%2 (base %12==0)

            // ---- 1. horizontal conv of row i (e[] read at iter i-1) ----
            v2f hSD = {0.f, 0.f}, hQ = {0.f, 0.f};
            #pragma unroll
            for (int j = 0; j < 11; ++j) {
                const v2f f = e[j] * e[j];          // v_pk_mul_f32
                hSD = pkfma(g[j], e[j], hSD);
                hQ  = pkfma(g[j], f,    hQ);
            }
            rSD[s] = hSD;
            rQ[s]  = hQ;

            // ---- 2. prefetch row i+1's window into e[] (dead after 1) ----
            // slot (i+1)%3 was written at iter i-1; consumed next iteration.
            if (i < ITERS - 1) {
                #pragma unroll
                for (int j = 0; j < 11; ++j)
                    e[j] = seg3[wv][(s + 1) % 3][lane + j];
            }

            // ---- 3. stage row i+2 from P[i%3] (loaded at iter i-3) ----
            if (i <= ITERS - 3) {
                if (s % 3 == 0)      WRITESLOT((s + 2) % 3, 0);
                else if (s % 3 == 1) WRITESLOT((s + 2) % 3, 1);
                else                 WRITESLOT((s + 2) % 3, 2);
            }

            // ---- 4. issue loads for row i+5 into P[i%3] (iter i+3) ----
            if (i <= ITERS - 6) {
                if (s % 3 == 0)      LOADROW(r0 + i, 0);
                else if (s % 3 == 1) LOADROW(r0 + i, 1);
                else                 LOADROW(r0 + i, 2);
            }

            // ---- 5. vertical conv + SSIM epilogue (row r0 + i - 10) ----
            if (i >= 10) {                       // wave-uniform
                const int orow = r0 + i - 10;
                if (orow < IMG_H) {              // wave-uniform tail guard
                    v2f mSD = {0.f, 0.f}, mQ = {0.f, 0.f};
                    #pragma unroll
                    for (int j = 0; j < 11; ++j) {
                        // input rows i-10+j -> ring slot (i+2+j)%12
                        const int sl = (s + 2 + j) % 12;   // static
                        mSD = pkfma(g[j], rSD[sl], mSD);
                        mQ  = pkfma(g[j], rQ[sl],  mQ);
                    }
                    const v2f t2 = mSD * mSD;      // (mS^2, mD^2)
                    const float a    = 0.5f  * (t2.x + t2.y); // mx2+my2
                    const float muxy = 0.25f * (t2.x - t2.y); // mx*my
                    const float ep   = 0.5f  * (mQ.x + mQ.y); // Ex2+Ey2
                    const float eq   = 0.25f * (mQ.x - mQ.y); // Exy
                    const float sxy  = eq - muxy;
                    const float ssum = ep - a;
                    const float num  = fmaf(2.f, muxy, C1F) * fmaf(2.f, sxy, C2F);
                    const float den  = (a + C1F) * (ssum + C2F);
                    float v = num * __builtin_amdgcn_rcpf(den + EPSF);
                    acc += fminf(fmaxf(v, 0.f), 1.f);
                }
            }
        }
    }

    // block reduction: wave shuffle, 4 slots in LDS, one atomic per block.
    // (The only __syncthreads in the kernel -- at the very end.)
    #pragma unroll
    for (int off = 32; off > 0; off >>= 1)
        acc += __shfl_down(acc, off, 64);
    if (lane == 0) wredS[wv] = acc;
    __syncthreads();
    if (t == 0) {
        const float tot = (wredS[0] + wredS[1]) + (wredS[2] + wredS[3]);
        atomicAdd(out, tot * (1.0f / (float)((size_t)NIMG * IMG_H * IMG_W)));
    }
}

extern "C" void kernel_launch(void* const* d_in, const int* in_sizes, int n_in,
                              void* d_out, int out_size, void* d_ws, size_t ws_size,
                              hipStream_t stream) {
    const float* x = (const float*)d_in[0];
    const float* y = (const float*)d_in[1];
    const float* w = (const float*)d_in[2];
    float* out = (float*)d_out;

    // d_out is re-poisoned to 0xAA before every timed launch; zero it first.
    hipMemsetAsync(out, 0, sizeof(float), stream);

    dim3 grid(NCHNK * 2, NIMG);    // (28, 32) = 896 blocks x 4 waves
    ssim_kernel<<<grid, dim3(NT), 0, stream>>>(x, y, w, out);
}